// Round 20
// baseline (86.235 us; speedup 1.0000x reference)
//
#include <hip/hip_runtime.h>
#include <hip/hip_bf16.h>
#include <math.h>

#define B 4
#define L 1024
#define D 256
#define H 8
#define HD 64

// workspace layout (float offsets)
#define KB_OFF  1048576                // Q bf16 [0, KB_OFF) floats
#define VR_OFF  2097152                // K bf16 [KB_OFF, VR_OFF); vr fp32 here
#define DP_OFF  (VR_OFF + 32768)       // Dpart fp32 [hb][dt 32][qt 32][64] (8 MB)
#define XP_OFF  (DP_OFF + 2097152)     // xpe bf16 [4096][256]
#define WT_OFF  (XP_OFF + 524288)      // WT bf16 [1024][256]
// total floats: WT_OFF + 131072 = 4882432 (~19.5 MB)

typedef short short8 __attribute__((ext_vector_type(8)));
typedef float f32x16 __attribute__((ext_vector_type(16)));

__device__ __forceinline__ unsigned short f2bf(float f) {
  __hip_bfloat16 h = __float2bfloat16(f);
  return *reinterpret_cast<unsigned short*>(&h);
}

// ---------------------------------------------------------------------------
// prep_wx: Blocks 0..31: WT transpose. Blocks 32..543: XP = bf16(x+pe);
//          vr[hb][k] = sigmoid(x@Wv) reversed (parallel: 4 thr per (row,h)).
// ---------------------------------------------------------------------------
__global__ __launch_bounds__(256) void prep_wx_kernel(
    const float* __restrict__ x, const float* __restrict__ Wq,
    const float* __restrict__ Wk, const float* __restrict__ Wv,
    const float* __restrict__ pe, float* __restrict__ ws)
{
  const int tid = threadIdx.x;
  if (blockIdx.x < 32) {
    __shared__ float lds[32][257];
    const int c0 = blockIdx.x * 32;
    const float* W = (c0 < 512) ? Wq : Wk;
    const int cc = c0 & 511;
    const int c = tid & 31, dd = tid >> 5;
    for (int d0 = 0; d0 < 256; d0 += 8)
      lds[c][d0 + dd] = W[(d0 + dd) * 512 + cc + c];
    __syncthreads();
    __hip_bfloat16* WT = (__hip_bfloat16*)(ws + WT_OFF);
    for (int cl = 0; cl < 32; ++cl)
      WT[(c0 + cl) * 256 + tid] = __float2bfloat16(lds[cl][tid]);
    return;
  }

  __shared__ float xs[8][257];
  const int r0 = (blockIdx.x - 32) * 8;
  __hip_bfloat16* XP = (__hip_bfloat16*)(ws + XP_OFF);
  for (int idx = tid; idx < 2048; idx += 256) {
    int rr = idx >> 8, c = idx & 255;
    int gr = r0 + rr, l = gr & 1023;
    float xv = x[gr * 256 + c];
    xs[rr][c] = xv;
    XP[gr * 256 + c] = __float2bfloat16(xv + pe[l * 256 + c]);
  }
  __syncthreads();
  {
    int rr = tid >> 5, h = (tid >> 2) & 7, t4 = tid & 3;
    float acc = 0.f;
    const int d0 = t4 << 6;
#pragma unroll 16
    for (int d = 0; d < 64; ++d) acc += xs[rr][d0 + d] * Wv[(d0 + d) * 8 + h];
    acc += __shfl_down(acc, 1, 4);
    acc += __shfl_down(acc, 2, 4);
    if (t4 == 0) {
      float v = 1.f / (1.f + __expf(-acc));
      int gr = r0 + rr;
      int b = gr >> 10, l = gr & 1023;
      ws[VR_OFF + (h * 4 + b) * 1024 + (1023 - l)] = v;
    }
  }
}

// ---------------------------------------------------------------------------
// qkgemm: Q|K = bf16(XP @ [Wq|Wk] + bias) via MFMA, written to [hb][l][64].
// ---------------------------------------------------------------------------
__global__ __launch_bounds__(256) void qkgemm_kernel(float* __restrict__ ws,
    const float* __restrict__ bq, const float* __restrict__ bk)
{
  const int tid = threadIdx.x;
  const int w = tid >> 6, lane = tid & 63;
  const int wid = blockIdx.x * 4 + w;
  const int lt = wid & 127;
  const int cp = wid >> 7;           // 0..15 (0..7 -> Q, 8..15 -> K)

  const __hip_bfloat16* XP = (const __hip_bfloat16*)(ws + XP_OFF);
  const __hip_bfloat16* WT = (const __hip_bfloat16*)(ws + WT_OFF);

  const int ln = (lt << 5) + (lane & 31);
  const int dlo = (lane >> 5) << 3;
  const int ca = (cp << 6) + (lane & 31);
  const __hip_bfloat16* xr = XP + ln * 256 + dlo;
  const __hip_bfloat16* ar = WT + ca * 256 + dlo;
  const __hip_bfloat16* br = ar + (32 * 256);

  f32x16 acca = {0.f,0.f,0.f,0.f,0.f,0.f,0.f,0.f,0.f,0.f,0.f,0.f,0.f,0.f,0.f,0.f};
  f32x16 accb = {0.f,0.f,0.f,0.f,0.f,0.f,0.f,0.f,0.f,0.f,0.f,0.f,0.f,0.f,0.f,0.f};
#pragma unroll
  for (int k = 0; k < 16; ++k) {
    short8 bf  = *(const short8*)(xr + k * 16);
    short8 afa = *(const short8*)(ar + k * 16);
    short8 afb = *(const short8*)(br + k * 16);
    acca = __builtin_amdgcn_mfma_f32_32x32x16_bf16(afa, bf, acca, 0, 0, 0);
    accb = __builtin_amdgcn_mfma_f32_32x32x16_bf16(afb, bf, accb, 0, 0, 0);
  }

  const int b = ln >> 10, l = ln & 1023;
  const int hq = cp & 7;
  const int hi4 = (lane >> 5) << 2;
  const float* bias = (cp < 8) ? bq : bk;
  const int cbase = hq << 6;
  __hip_bfloat16* base = (__hip_bfloat16*)ws + ((cp < 8) ? 0 : (size_t)KB_OFF * 2);
  __hip_bfloat16* dst = base + ((((size_t)(hq * 4 + b) << 10) + l) << 6);

#pragma unroll
  for (int q = 0; q < 4; ++q) {
    int hd0 = (q << 3) + hi4;
    float4 bv = *(const float4*)(bias + cbase + hd0);
    ushort4 pk;
    pk.x = f2bf(acca[4 * q + 0] + bv.x);
    pk.y = f2bf(acca[4 * q + 1] + bv.y);
    pk.z = f2bf(acca[4 * q + 2] + bv.z);
    pk.w = f2bf(acca[4 * q + 3] + bv.w);
    *(ushort4*)(dst + hd0) = pk;

    int hd1 = hd0 + 32;
    float4 bw = *(const float4*)(bias + cbase + hd1);
    ushort4 pk2;
    pk2.x = f2bf(accb[4 * q + 0] + bw.x);
    pk2.y = f2bf(accb[4 * q + 1] + bw.y);
    pk2.z = f2bf(accb[4 * q + 2] + bw.z);
    pk2.w = f2bf(accb[4 * q + 3] + bw.w);
    *(ushort4*)(dst + hd1) = pk2;
  }
}

// ---------------------------------------------------------------------------
// attn (fused, zero atomics, LDS = 512B): one block per (qt, hb), 4 waves.
// Phase 1: full 32-tile sweep (8/wave, 4-chain, 4 exp accumulators) -> inv.
// Phase 2: wave w, paired tiles (dt, dt+4) stride 8: MFMA -> p = exp*vr*inv
//   in REGISTERS -> pure-shfl diagonal gather (verified r16 mapping) ->
//   one coalesced 256B store per tile into unique Dpart[hb][dt][qt][64].
// Grid 1024 = (qt 32) x (hb 32); hb = i&31 -> XCD-pinned.
// ---------------------------------------------------------------------------
__global__ __launch_bounds__(256) void attn_kernel(float* __restrict__ ws)
{
  __shared__ float smerge[4][32];
  const int tid = threadIdx.x;
  const int w = tid >> 6, lane = tid & 63;
  const int i = blockIdx.x;
  const int hb = i & 31;
  const int qt = i >> 5;

  const __hip_bfloat16* Qb = (const __hip_bfloat16*)ws + ((size_t)hb << 16);
  const __hip_bfloat16* Kb = (const __hip_bfloat16*)(ws + KB_OFF) + ((size_t)hb << 16);
  const float* __restrict__ vr = ws + VR_OFF + (hb << 10);

  const int qrow = (qt << 5) + (lane & 31);
  const int dlo = (lane >> 5) << 3;
  const int coff = (lane >> 5) << 2;

  const __hip_bfloat16* qr = Qb + (qrow << 6) + dlo;
  short8 qf0 = *(const short8*)(qr);
  short8 qf1 = *(const short8*)(qr + 16);
  short8 qf2 = *(const short8*)(qr + 32);
  short8 qf3 = *(const short8*)(qr + 48);

#define GLOADK(kt, kf)                                                        \
  {                                                                           \
    const __hip_bfloat16* kr_ = Kb + ((((kt) << 5) + (lane & 31)) << 6) + dlo;\
    kf[0] = *(const short8*)(kr_);                                            \
    kf[1] = *(const short8*)(kr_ + 16);                                       \
    kf[2] = *(const short8*)(kr_ + 32);                                       \
    kf[3] = *(const short8*)(kr_ + 48);                                       \
  }

  // ---- phase 1: denominator, 8 tiles/wave, 4 chains, 4 exp accumulators ----
  float sp0 = 0.f, sp1 = 0.f, sp2 = 0.f, sp3 = 0.f;
#pragma unroll
  for (int t = 0; t < 2; ++t) {
    const int kt0 = w + (t << 2);
    short8 kA[4], kB[4], kC[4], kD[4];
    GLOADK(kt0, kA);
    GLOADK(kt0 + 8, kB);
    GLOADK(kt0 + 16, kC);
    GLOADK(kt0 + 24, kD);
    f32x16 aA = {0.f,0.f,0.f,0.f,0.f,0.f,0.f,0.f,0.f,0.f,0.f,0.f,0.f,0.f,0.f,0.f};
    f32x16 aB = {0.f,0.f,0.f,0.f,0.f,0.f,0.f,0.f,0.f,0.f,0.f,0.f,0.f,0.f,0.f,0.f};
    f32x16 aC = {0.f,0.f,0.f,0.f,0.f,0.f,0.f,0.f,0.f,0.f,0.f,0.f,0.f,0.f,0.f,0.f};
    f32x16 aD = {0.f,0.f,0.f,0.f,0.f,0.f,0.f,0.f,0.f,0.f,0.f,0.f,0.f,0.f,0.f,0.f};
#pragma unroll
    for (int s = 0; s < 4; ++s) {
      short8 qs = (s == 0) ? qf0 : (s == 1) ? qf1 : (s == 2) ? qf2 : qf3;
      aA = __builtin_amdgcn_mfma_f32_32x32x16_bf16(kA[s], qs, aA, 0, 0, 0);
      aB = __builtin_amdgcn_mfma_f32_32x32x16_bf16(kB[s], qs, aB, 0, 0, 0);
      aC = __builtin_amdgcn_mfma_f32_32x32x16_bf16(kC[s], qs, aC, 0, 0, 0);
      aD = __builtin_amdgcn_mfma_f32_32x32x16_bf16(kD[s], qs, aD, 0, 0, 0);
    }
#pragma unroll
    for (int r = 0; r < 16; ++r) {
      sp0 += __expf(aA[r] * 0.125f);
      sp1 += __expf(aB[r] * 0.125f);
      sp2 += __expf(aC[r] * 0.125f);
      sp3 += __expf(aD[r] * 0.125f);
    }
  }
  float s_part = (sp0 + sp1) + (sp2 + sp3);
  s_part += __shfl_xor(s_part, 32);
  if (lane < 32) smerge[w][lane] = s_part;
  __syncthreads();
  const int q = lane & 31;
  const float inv = 1.f / (smerge[0][q] + smerge[1][q] + smerge[2][q] + smerge[3][q]);

  // per-tile epilogue: p in regs -> shfl gather -> direct coalesced store.
  // slot s sums p[r] from src lane (hi<<5)+km+31-s, km = hi*4+(r&3)+8*(r>>2),
  // gated km <= s && km >= s-31  (verified r16 mapping).
#define FLUSH(dt_, acc_)                                                      \
  {                                                                           \
    const int kt_ = qt + (dt_);                                               \
    const float* vb_ = vr + (kt_ << 5) + coff;                                \
    float4 v0_ = *(const float4*)(vb_);                                       \
    float4 v1_ = *(const float4*)(vb_ + 8);                                   \
    float4 v2_ = *(const float4*)(vb_ + 16);                                  \
    float4 v3_ = *(const float4*)(vb_ + 24);                                  \
    float p_[16];                                                             \
    _Pragma("unroll")                                                         \
    for (int r = 0; r < 16; ++r) {                                            \
      float vv_ = (r < 4) ? (&v0_.x)[r] : (r < 8) ? (&v1_.x)[r - 4]           \
                : (r < 12) ? (&v2_.x)[r - 8] : (&v3_.x)[r - 12];              \
      p_[r] = __expf(acc_[r] * 0.125f) * vv_ * inv;                           \
    }                                                                         \
    float accg_ = 0.f;                                                        \
    _Pragma("unroll")                                                         \
    for (int hi = 0; hi < 2; ++hi)                                            \
      _Pragma("unroll")                                                       \
      for (int r = 0; r < 16; ++r) {                                          \
        const int km_ = (hi << 2) + (r & 3) + ((r >> 2) << 3);                \
        int src_ = ((hi << 5) + km_ + 31 - lane) & 63;                        \
        float g_ = __shfl(p_[r], src_);                                       \
        if (km_ <= lane && km_ >= lane - 31) accg_ += g_;                     \
      }                                                                       \
    ws[DP_OFF + ((((hb << 5) + (dt_)) << 5) + qt) * 64 + lane] = accg_;       \
  }

  // ---- phase 2: paired tiles (dt, dt+4), stride 8 ----
  const int dtmax = 31 - qt;
  for (int dt = w; dt <= dtmax; dt += 8) {
    const int dt2 = dt + 4;
    const bool has2 = (dt2 <= dtmax);
    const int kta = qt + dt;
    const int ktb = qt + (has2 ? dt2 : dt);
    short8 ka[4], kb[4];
    GLOADK(kta, ka);
    GLOADK(ktb, kb);
    f32x16 acca = {0.f,0.f,0.f,0.f,0.f,0.f,0.f,0.f,0.f,0.f,0.f,0.f,0.f,0.f,0.f,0.f};
    f32x16 accb = {0.f,0.f,0.f,0.f,0.f,0.f,0.f,0.f,0.f,0.f,0.f,0.f,0.f,0.f,0.f,0.f};
    acca = __builtin_amdgcn_mfma_f32_32x32x16_bf16(ka[0], qf0, acca, 0, 0, 0);
    accb = __builtin_amdgcn_mfma_f32_32x32x16_bf16(kb[0], qf0, accb, 0, 0, 0);
    acca = __builtin_amdgcn_mfma_f32_32x32x16_bf16(ka[1], qf1, acca, 0, 0, 0);
    accb = __builtin_amdgcn_mfma_f32_32x32x16_bf16(kb[1], qf1, accb, 0, 0, 0);
    acca = __builtin_amdgcn_mfma_f32_32x32x16_bf16(ka[2], qf2, acca, 0, 0, 0);
    accb = __builtin_amdgcn_mfma_f32_32x32x16_bf16(kb[2], qf2, accb, 0, 0, 0);
    acca = __builtin_amdgcn_mfma_f32_32x32x16_bf16(ka[3], qf3, acca, 0, 0, 0);
    accb = __builtin_amdgcn_mfma_f32_32x32x16_bf16(kb[3], qf3, accb, 0, 0, 0);
    FLUSH(dt, acca);
    if (has2) FLUSH(dt2, accb);
  }
}

// ---------------------------------------------------------------------------
// out: T[hb][j] = sum over dt in {d, d-1} and qt <= 31-dt of
//      Dpart[hb][dt][qt][j - 32*dt + 31]; then window3 / cnt.
// Grid 256 = (jc 8) x (hb 32).
// ---------------------------------------------------------------------------
__global__ __launch_bounds__(256) void out_kernel(const float* __restrict__ ws,
                                                  float* __restrict__ out)
{
  __shared__ float s[130];
  const int tid = threadIdx.x;
  const int i = blockIdx.x;
  const int hb = i & 31;
  const int jc = i >> 5;
  const int j0 = jc << 7;
  const float* DP = ws + DP_OFF + ((size_t)hb << 16);   // hb*32*32*64

  if (tid < 130) {
    int jj = j0 + tid - 1;
    float acc = 0.f;
    if (jj >= 0 && jj < 1024) {
      int dthi = (jj + 31) >> 5;
#pragma unroll
      for (int cand = 0; cand < 2; ++cand) {
        int dt = dthi - cand;
        if (dt < 0 || dt > 31) continue;
        int idx = jj - (dt << 5) + 31;
        if (idx < 0 || idx > 63) continue;
        const float* base = DP + (dt << 11) + idx;      // dt*32*64
        int nq = 32 - dt;
        for (int qc = 0; qc < nq; ++qc)
          acc += base[qc << 6];
      }
    }
    s[tid] = acc;
  }
  __syncthreads();
  if (tid < 128) {
    int j = j0 + tid;
    float cnt = (j == 0 || j == 1023) ? 2.f : 3.f;
    float v = (s[tid] + s[tid + 1] + s[tid + 2]) / cnt;
    int h = hb >> 2, b = hb & 3;
    out[(((b << 10) + j) << 3) + h] = v;
  }
}

extern "C" void kernel_launch(void* const* d_in, const int* in_sizes, int n_in,
                              void* d_out, int out_size, void* d_ws, size_t ws_size,
                              hipStream_t stream)
{
  const float* x  = (const float*)d_in[0];
  const float* Wq = (const float*)d_in[1];
  const float* bq = (const float*)d_in[2];
  const float* Wk = (const float*)d_in[3];
  const float* bk = (const float*)d_in[4];
  const float* Wv = (const float*)d_in[5];
  const float* pe = (const float*)d_in[6];
  float* ws = (float*)d_ws;
  float* out = (float*)d_out;

  prep_wx_kernel<<<dim3(544), dim3(256), 0, stream>>>(x, Wq, Wk, Wv, pe, ws);
  qkgemm_kernel<<<dim3(512), dim3(256), 0, stream>>>(ws, bq, bk);
  attn_kernel<<<dim3(1024), dim3(256), 0, stream>>>(ws);
  out_kernel<<<dim3(256), dim3(256), 0, stream>>>(ws, out);
}

// Round 21
// 61.444 us; speedup vs baseline: 1.4035x; 1.4035x over previous
//
#include <hip/hip_runtime.h>
#include <hip/hip_bf16.h>
#include <math.h>

#define B 4
#define L 1024
#define D 256
#define H 8
#define HD 64

// workspace layout (float offsets)
#define KB_OFF  1048576                // Q bf16 [0, KB_OFF) floats
#define VR_OFF  2097152                // K bf16 [KB_OFF, VR_OFF); vr fp32 here
#define TP2_OFF (VR_OFF + 32768)       // Tpart2 fp32 [hb][qt 32][dt 32][64] (8 MB)
#define T_OFF   (TP2_OFF + 2097152)    // T fp32 [hb][1024]
#define XP_OFF  (T_OFF + 32768)        // xpe bf16 [4096][256]
#define WT_OFF  (XP_OFF + 524288)      // WT bf16 [1024][256]
// total floats: WT_OFF + 131072 = 4915200 (~19.7 MB)

typedef short short8 __attribute__((ext_vector_type(8)));
typedef float f32x16 __attribute__((ext_vector_type(16)));

__device__ __forceinline__ unsigned short f2bf(float f) {
  __hip_bfloat16 h = __float2bfloat16(f);
  return *reinterpret_cast<unsigned short*>(&h);
}

// ---------------------------------------------------------------------------
// prep_wx: Blocks 0..31: WT transpose. Blocks 32..543: XP = bf16(x+pe);
//          vr[hb][k] = sigmoid(x@Wv) reversed (parallel: 4 thr per (row,h)).
// ---------------------------------------------------------------------------
__global__ __launch_bounds__(256) void prep_wx_kernel(
    const float* __restrict__ x, const float* __restrict__ Wq,
    const float* __restrict__ Wk, const float* __restrict__ Wv,
    const float* __restrict__ pe, float* __restrict__ ws)
{
  const int tid = threadIdx.x;
  if (blockIdx.x < 32) {
    __shared__ float lds[32][257];
    const int c0 = blockIdx.x * 32;
    const float* W = (c0 < 512) ? Wq : Wk;
    const int cc = c0 & 511;
    const int c = tid & 31, dd = tid >> 5;
    for (int d0 = 0; d0 < 256; d0 += 8)
      lds[c][d0 + dd] = W[(d0 + dd) * 512 + cc + c];
    __syncthreads();
    __hip_bfloat16* WT = (__hip_bfloat16*)(ws + WT_OFF);
    for (int cl = 0; cl < 32; ++cl)
      WT[(c0 + cl) * 256 + tid] = __float2bfloat16(lds[cl][tid]);
    return;
  }

  __shared__ float xs[8][257];
  const int r0 = (blockIdx.x - 32) * 8;
  __hip_bfloat16* XP = (__hip_bfloat16*)(ws + XP_OFF);
  for (int idx = tid; idx < 2048; idx += 256) {
    int rr = idx >> 8, c = idx & 255;
    int gr = r0 + rr, l = gr & 1023;
    float xv = x[gr * 256 + c];
    xs[rr][c] = xv;
    XP[gr * 256 + c] = __float2bfloat16(xv + pe[l * 256 + c]);
  }
  __syncthreads();
  {
    int rr = tid >> 5, h = (tid >> 2) & 7, t4 = tid & 3;
    float acc = 0.f;
    const int d0 = t4 << 6;
#pragma unroll 16
    for (int d = 0; d < 64; ++d) acc += xs[rr][d0 + d] * Wv[(d0 + d) * 8 + h];
    acc += __shfl_down(acc, 1, 4);
    acc += __shfl_down(acc, 2, 4);
    if (t4 == 0) {
      float v = 1.f / (1.f + __expf(-acc));
      int gr = r0 + rr;
      int b = gr >> 10, l = gr & 1023;
      ws[VR_OFF + (h * 4 + b) * 1024 + (1023 - l)] = v;
    }
  }
}

// ---------------------------------------------------------------------------
// qkgemm: Q|K = bf16(XP @ [Wq|Wk] + bias) via MFMA, written to [hb][l][64].
// ---------------------------------------------------------------------------
__global__ __launch_bounds__(256) void qkgemm_kernel(float* __restrict__ ws,
    const float* __restrict__ bq, const float* __restrict__ bk)
{
  const int tid = threadIdx.x;
  const int w = tid >> 6, lane = tid & 63;
  const int wid = blockIdx.x * 4 + w;
  const int lt = wid & 127;
  const int cp = wid >> 7;           // 0..15 (0..7 -> Q, 8..15 -> K)

  const __hip_bfloat16* XP = (const __hip_bfloat16*)(ws + XP_OFF);
  const __hip_bfloat16* WT = (const __hip_bfloat16*)(ws + WT_OFF);

  const int ln = (lt << 5) + (lane & 31);
  const int dlo = (lane >> 5) << 3;
  const int ca = (cp << 6) + (lane & 31);
  const __hip_bfloat16* xr = XP + ln * 256 + dlo;
  const __hip_bfloat16* ar = WT + ca * 256 + dlo;
  const __hip_bfloat16* br = ar + (32 * 256);

  f32x16 acca = {0.f,0.f,0.f,0.f,0.f,0.f,0.f,0.f,0.f,0.f,0.f,0.f,0.f,0.f,0.f,0.f};
  f32x16 accb = {0.f,0.f,0.f,0.f,0.f,0.f,0.f,0.f,0.f,0.f,0.f,0.f,0.f,0.f,0.f,0.f};
#pragma unroll
  for (int k = 0; k < 16; ++k) {
    short8 bf  = *(const short8*)(xr + k * 16);
    short8 afa = *(const short8*)(ar + k * 16);
    short8 afb = *(const short8*)(br + k * 16);
    acca = __builtin_amdgcn_mfma_f32_32x32x16_bf16(afa, bf, acca, 0, 0, 0);
    accb = __builtin_amdgcn_mfma_f32_32x32x16_bf16(afb, bf, accb, 0, 0, 0);
  }

  const int b = ln >> 10, l = ln & 1023;
  const int hq = cp & 7;
  const int hi4 = (lane >> 5) << 2;
  const float* bias = (cp < 8) ? bq : bk;
  const int cbase = hq << 6;
  __hip_bfloat16* base = (__hip_bfloat16*)ws + ((cp < 8) ? 0 : (size_t)KB_OFF * 2);
  __hip_bfloat16* dst = base + ((((size_t)(hq * 4 + b) << 10) + l) << 6);

#pragma unroll
  for (int q = 0; q < 4; ++q) {
    int hd0 = (q << 3) + hi4;
    float4 bv = *(const float4*)(bias + cbase + hd0);
    ushort4 pk;
    pk.x = f2bf(acca[4 * q + 0] + bv.x);
    pk.y = f2bf(acca[4 * q + 1] + bv.y);
    pk.z = f2bf(acca[4 * q + 2] + bv.z);
    pk.w = f2bf(acca[4 * q + 3] + bv.w);
    *(ushort4*)(dst + hd0) = pk;

    int hd1 = hd0 + 32;
    float4 bw = *(const float4*)(bias + cbase + hd1);
    ushort4 pk2;
    pk2.x = f2bf(accb[4 * q + 0] + bw.x);
    pk2.y = f2bf(accb[4 * q + 1] + bw.y);
    pk2.z = f2bf(accb[4 * q + 2] + bw.z);
    pk2.w = f2bf(accb[4 * q + 3] + bw.w);
    *(ushort4*)(dst + hd1) = pk2;
  }
}

// ---------------------------------------------------------------------------
// attn: one block per (qt, hb), 4 waves, LDS 32.5 KB -> 4 blocks/CU.
// qt remapped so each CU's 4 blocks have balanced phase-2 work (66 tiles).
// K staged per 8-tile chunk (32 KB): coalesced float4 + XOR swizzle (r13).
// Phase 1: 4 chunks; per chunk wave w computes tiles w, w+4 (2-chain).
// Phase 2: chunks descending from 3 (resident) to qt/8; per tile:
//   MFMA -> p = exp*vr*inv in regs -> shfl diagonal gather (r20-verified)
//   -> direct coalesced 256B store to Tpart2[hb][qt][dt][64]. Zero atomics.
// ---------------------------------------------------------------------------
__global__ __launch_bounds__(256) void attn_kernel(float* __restrict__ ws)
{
  __shared__ __hip_bfloat16 Ks[256 * 64];   // 32 KB chunk buffer (swizzled)
  __shared__ float smerge[4][32];
  const int tid = threadIdx.x;
  const int w = tid >> 6, lane = tid & 63;
  const int i = blockIdx.x;
  const int hb = i & 31;
  const int j = i >> 5;
  // balance remap: per-CU {j0, 23-(j0+8), j0+16, 55-(j0+24)} = {j0,15-j0,16+j0,31-j0}
  const int qt = (j & 8) ? ((j < 16) ? 23 - j : 55 - j) : j;

  const __hip_bfloat16* Qb = (const __hip_bfloat16*)ws + ((size_t)hb << 16);
  const __hip_bfloat16* Kb = (const __hip_bfloat16*)(ws + KB_OFF) + ((size_t)hb << 16);
  const float* __restrict__ vr = ws + VR_OFF + (hb << 10);

  const int qrow = (qt << 5) + (lane & 31);
  const int dlo = (lane >> 5) << 3;
  const int coff = (lane >> 5) << 2;

  const __hip_bfloat16* qr = Qb + (qrow << 6) + dlo;
  short8 qf0 = *(const short8*)(qr);
  short8 qf1 = *(const short8*)(qr + 16);
  short8 qf2 = *(const short8*)(qr + 32);
  short8 qf3 = *(const short8*)(qr + 48);

  // stage chunk c (tiles 8c..8c+7; 256 rows x 128B) with XOR swizzle
#define STAGE8(c)                                                             \
  {                                                                           \
    const float4* src_ = (const float4*)Kb + ((c) << 11);                     \
    _Pragma("unroll")                                                         \
    for (int u = 0; u < 8; ++u) {                                             \
      int idx_ = (u << 8) + tid;                                              \
      float4 v_ = src_[idx_];                                                 \
      int row_ = idx_ >> 3;                                                   \
      int colb_ = (idx_ & 7) << 4;                                            \
      *(float4*)((char*)Ks + row_ * 128 + (colb_ ^ ((row_ & 7) << 4))) = v_;  \
    }                                                                         \
  }

  // load 4 fragments of tile tl (0..7 within chunk) from swizzled LDS
#define LDK(tl, kf)                                                           \
  {                                                                           \
    int row_ = ((tl) << 5) + (lane & 31);                                     \
    int sw_ = (row_ & 7) << 4;                                                \
    int cb_ = (lane >> 5) << 4;                                               \
    char* bp_ = (char*)Ks + row_ * 128;                                       \
    kf[0] = *(const short8*)(bp_ + ((cb_) ^ sw_));                            \
    kf[1] = *(const short8*)(bp_ + ((cb_ + 32) ^ sw_));                       \
    kf[2] = *(const short8*)(bp_ + ((cb_ + 64) ^ sw_));                       \
    kf[3] = *(const short8*)(bp_ + ((cb_ + 96) ^ sw_));                       \
  }

  // ---- phase 1: denominator over 4 chunks; wave does tiles w, w+4 ----
  float sp0 = 0.f, sp1 = 0.f, sp2 = 0.f, sp3 = 0.f;
  for (int c = 0; c < 4; ++c) {
    if (c) __syncthreads();
    STAGE8(c);
    __syncthreads();
    short8 ka[4], kb[4];
    LDK(w, ka);
    LDK(w + 4, kb);
    f32x16 acca = {0.f,0.f,0.f,0.f,0.f,0.f,0.f,0.f,0.f,0.f,0.f,0.f,0.f,0.f,0.f,0.f};
    f32x16 accb = {0.f,0.f,0.f,0.f,0.f,0.f,0.f,0.f,0.f,0.f,0.f,0.f,0.f,0.f,0.f,0.f};
    acca = __builtin_amdgcn_mfma_f32_32x32x16_bf16(ka[0], qf0, acca, 0, 0, 0);
    accb = __builtin_amdgcn_mfma_f32_32x32x16_bf16(kb[0], qf0, accb, 0, 0, 0);
    acca = __builtin_amdgcn_mfma_f32_32x32x16_bf16(ka[1], qf1, acca, 0, 0, 0);
    accb = __builtin_amdgcn_mfma_f32_32x32x16_bf16(kb[1], qf1, accb, 0, 0, 0);
    acca = __builtin_amdgcn_mfma_f32_32x32x16_bf16(ka[2], qf2, acca, 0, 0, 0);
    accb = __builtin_amdgcn_mfma_f32_32x32x16_bf16(kb[2], qf2, accb, 0, 0, 0);
    acca = __builtin_amdgcn_mfma_f32_32x32x16_bf16(ka[3], qf3, acca, 0, 0, 0);
    accb = __builtin_amdgcn_mfma_f32_32x32x16_bf16(kb[3], qf3, accb, 0, 0, 0);
#pragma unroll
    for (int r = 0; r < 16; r += 2) {
      sp0 += __expf(acca[r] * 0.125f);
      sp1 += __expf(acca[r + 1] * 0.125f);
      sp2 += __expf(accb[r] * 0.125f);
      sp3 += __expf(accb[r + 1] * 0.125f);
    }
  }
  float s_part = (sp0 + sp1) + (sp2 + sp3);
  s_part += __shfl_xor(s_part, 32);
  if (lane < 32) smerge[w][lane] = s_part;
  __syncthreads();
  const int q = lane & 31;
  const float inv = 1.f / (smerge[0][q] + smerge[1][q] + smerge[2][q] + smerge[3][q]);

  // per-tile epilogue: p in regs -> shfl gather (r20-verified) -> direct store
#define FLUSH(dt_, acc_)                                                      \
  {                                                                           \
    const int kt_ = qt + (dt_);                                               \
    const float* vb_ = vr + (kt_ << 5) + coff;                                \
    float4 v0_ = *(const float4*)(vb_);                                       \
    float4 v1_ = *(const float4*)(vb_ + 8);                                   \
    float4 v2_ = *(const float4*)(vb_ + 16);                                  \
    float4 v3_ = *(const float4*)(vb_ + 24);                                  \
    float p_[16];                                                             \
    _Pragma("unroll")                                                         \
    for (int r = 0; r < 16; ++r) {                                            \
      float vv_ = (r < 4) ? (&v0_.x)[r] : (r < 8) ? (&v1_.x)[r - 4]           \
                : (r < 12) ? (&v2_.x)[r - 8] : (&v3_.x)[r - 12];              \
      p_[r] = __expf(acc_[r] * 0.125f) * vv_ * inv;                           \
    }                                                                         \
    float accg_ = 0.f;                                                        \
    _Pragma("unroll")                                                         \
    for (int hi = 0; hi < 2; ++hi)                                            \
      _Pragma("unroll")                                                       \
      for (int r = 0; r < 16; ++r) {                                          \
        const int km_ = (hi << 2) + (r & 3) + ((r >> 2) << 3);                \
        int src_ = ((hi << 5) + km_ + 31 - lane) & 63;                        \
        float g_ = __shfl(p_[r], src_);                                       \
        if (km_ <= lane && km_ >= lane - 31) accg_ += g_;                     \
      }                                                                       \
    ws[TP2_OFF + ((size_t)hb << 16) + ((((qt) << 5) + (dt_)) << 6) + lane] = accg_; \
  }

  // ---- phase 2: chunks descending; chunk 3 still resident ----
  const int c0 = qt >> 3;
  for (int c = 3; c >= c0; --c) {
    if (c != 3) {
      __syncthreads();
      STAGE8(c);
      __syncthreads();
    }
    const int kta = (c << 3) + w;
    const int ktb = kta + 4;
    if (kta >= qt) {
      short8 ka[4], kb[4];
      LDK(w, ka);
      LDK(w + 4, kb);
      f32x16 acca = {0.f,0.f,0.f,0.f,0.f,0.f,0.f,0.f,0.f,0.f,0.f,0.f,0.f,0.f,0.f,0.f};
      f32x16 accb = {0.f,0.f,0.f,0.f,0.f,0.f,0.f,0.f,0.f,0.f,0.f,0.f,0.f,0.f,0.f,0.f};
      acca = __builtin_amdgcn_mfma_f32_32x32x16_bf16(ka[0], qf0, acca, 0, 0, 0);
      accb = __builtin_amdgcn_mfma_f32_32x32x16_bf16(kb[0], qf0, accb, 0, 0, 0);
      acca = __builtin_amdgcn_mfma_f32_32x32x16_bf16(ka[1], qf1, acca, 0, 0, 0);
      accb = __builtin_amdgcn_mfma_f32_32x32x16_bf16(kb[1], qf1, accb, 0, 0, 0);
      acca = __builtin_amdgcn_mfma_f32_32x32x16_bf16(ka[2], qf2, acca, 0, 0, 0);
      accb = __builtin_amdgcn_mfma_f32_32x32x16_bf16(kb[2], qf2, accb, 0, 0, 0);
      acca = __builtin_amdgcn_mfma_f32_32x32x16_bf16(ka[3], qf3, acca, 0, 0, 0);
      accb = __builtin_amdgcn_mfma_f32_32x32x16_bf16(kb[3], qf3, accb, 0, 0, 0);
      FLUSH(kta - qt, acca);
      FLUSH(ktb - qt, accb);
    } else if (ktb >= qt) {
      short8 kb[4];
      LDK(w + 4, kb);
      f32x16 accb = {0.f,0.f,0.f,0.f,0.f,0.f,0.f,0.f,0.f,0.f,0.f,0.f,0.f,0.f,0.f,0.f};
      accb = __builtin_amdgcn_mfma_f32_32x32x16_bf16(kb[0], qf0, accb, 0, 0, 0);
      accb = __builtin_amdgcn_mfma_f32_32x32x16_bf16(kb[1], qf1, accb, 0, 0, 0);
      accb = __builtin_amdgcn_mfma_f32_32x32x16_bf16(kb[2], qf2, accb, 0, 0, 0);
      accb = __builtin_amdgcn_mfma_f32_32x32x16_bf16(kb[3], qf3, accb, 0, 0, 0);
      FLUSH(ktb - qt, accb);
    }
  }
}

// ---------------------------------------------------------------------------
// out1: T[hb][j] = sum over cands dt in {d, d-1} (d = (j+31)>>5) and
//       qt <= 31-dt of Tpart2[hb][qt][dt][j-32dt+31]. 8 threads per j,
//       qt split across them, shfl-reduce. Grid 1024 = (jc 32) x (hb 32).
// ---------------------------------------------------------------------------
__global__ __launch_bounds__(256) void out1_kernel(float* __restrict__ ws)
{
  const int tid = threadIdx.x;
  const int i = blockIdx.x;
  const int hb = i & 31;
  const int jc = i >> 5;
  const int jj = (jc << 5) + (tid >> 3);
  const int t8 = tid & 7;
  const float* TP = ws + TP2_OFF + ((size_t)hb << 16);

  float acc = 0.f;
  const int s = jj + 31;
#pragma unroll
  for (int cand = 0; cand < 2; ++cand) {
    int dt = (s >> 5) - cand;
    if (dt < 0 || dt > 31) continue;
    int idx = s - (dt << 5);
    int qmax = 31 - dt;
    for (int qt = t8; qt <= qmax; qt += 8)
      acc += TP[(((qt << 5) + dt) << 6) + idx];
  }
  acc += __shfl_down(acc, 4, 8);
  acc += __shfl_down(acc, 2, 8);
  acc += __shfl_down(acc, 1, 8);
  if (t8 == 0) ws[T_OFF + (hb << 10) + jj] = acc;
}

// ---------------------------------------------------------------------------
// out2: out[b,j,h] = window3(T[hb]) / cnt. Grid 256 = (jc 8) x (hb 32).
// ---------------------------------------------------------------------------
__global__ __launch_bounds__(256) void out2_kernel(const float* __restrict__ ws,
                                                   float* __restrict__ out)
{
  __shared__ float s[130];
  const int tid = threadIdx.x;
  const int i = blockIdx.x;
  const int hb = i & 31;
  const int jc = i >> 5;
  const int j0 = jc << 7;
  const float* T = ws + T_OFF + (hb << 10);

  if (tid < 130) {
    int j = j0 + tid - 1;
    s[tid] = (j >= 0 && j < 1024) ? T[j] : 0.f;
  }
  __syncthreads();
  if (tid < 128) {
    int j = j0 + tid;
    float cnt = (j == 0 || j == 1023) ? 2.f : 3.f;
    float v = (s[tid] + s[tid + 1] + s[tid + 2]) / cnt;
    int h = hb >> 2, b = hb & 3;
    out[(((b << 10) + j) << 3) + h] = v;
  }
}

extern "C" void kernel_launch(void* const* d_in, const int* in_sizes, int n_in,
                              void* d_out, int out_size, void* d_ws, size_t ws_size,
                              hipStream_t stream)
{
  const float* x  = (const float*)d_in[0];
  const float* Wq = (const float*)d_in[1];
  const float* bq = (const float*)d_in[2];
  const float* Wk = (const float*)d_in[3];
  const float* bk = (const float*)d_in[4];
  const float* Wv = (const float*)d_in[5];
  const float* pe = (const float*)d_in[6];
  float* ws = (float*)d_ws;
  float* out = (float*)d_out;

  prep_wx_kernel<<<dim3(544), dim3(256), 0, stream>>>(x, Wq, Wk, Wv, pe, ws);
  qkgemm_kernel<<<dim3(512), dim3(256), 0, stream>>>(ws, bq, bk);
  attn_kernel<<<dim3(1024), dim3(256), 0, stream>>>(ws);
  out1_kernel<<<dim3(1024), dim3(256), 0, stream>>>(ws);
  out2_kernel<<<dim3(256), dim3(256), 0, stream>>>(ws, out);
}

// Round 23
// 59.310 us; speedup vs baseline: 1.4540x; 1.0360x over previous
//
#include <hip/hip_runtime.h>
#include <hip/hip_bf16.h>
#include <math.h>

#define B 4
#define L 1024
#define D 256
#define H 8
#define HD 64

// workspace layout (float offsets)
#define KB_OFF  1048576                // Q bf16 [0, KB_OFF) floats
#define VR_OFF  2097152                // K bf16 [KB_OFF, VR_OFF); vr fp32 here
#define TP2_OFF (VR_OFF + 32768)       // Tpart2 fp32 [hb][qt 32][dt 32][64] (8 MB)
#define XP_OFF  (TP2_OFF + 2097152)    // xpe bf16 [4096][256]
#define WT_OFF  (XP_OFF + 524288)      // WT bf16 [1024][256]
// total floats: WT_OFF + 131072 = 4882432 (~19.5 MB)

typedef short short8 __attribute__((ext_vector_type(8)));
typedef float f32x16 __attribute__((ext_vector_type(16)));

__device__ __forceinline__ unsigned short f2bf(float f) {
  __hip_bfloat16 h = __float2bfloat16(f);
  return *reinterpret_cast<unsigned short*>(&h);
}

// ---------------------------------------------------------------------------
// prep_wx: Blocks 0..31: WT transpose. Blocks 32..543: XP = bf16(x+pe)
//          (float4 loads, ushort4 stores); vr = sigmoid(x@Wv) reversed.
// ---------------------------------------------------------------------------
__global__ __launch_bounds__(256) void prep_wx_kernel(
    const float* __restrict__ x, const float* __restrict__ Wq,
    const float* __restrict__ Wk, const float* __restrict__ Wv,
    const float* __restrict__ pe, float* __restrict__ ws)
{
  const int tid = threadIdx.x;
  if (blockIdx.x < 32) {
    __shared__ float lds[32][257];
    const int c0 = blockIdx.x * 32;
    const float* W = (c0 < 512) ? Wq : Wk;
    const int cc = c0 & 511;
    const int c = tid & 31, dd = tid >> 5;
    for (int d0 = 0; d0 < 256; d0 += 8)
      lds[c][d0 + dd] = W[(d0 + dd) * 512 + cc + c];
    __syncthreads();
    __hip_bfloat16* WT = (__hip_bfloat16*)(ws + WT_OFF);
    for (int cl = 0; cl < 32; ++cl)
      WT[(c0 + cl) * 256 + tid] = __float2bfloat16(lds[cl][tid]);
    return;
  }

  __shared__ float xs[8][257];
  const int r0 = (blockIdx.x - 32) * 8;
  __hip_bfloat16* XP = (__hip_bfloat16*)(ws + XP_OFF);
#pragma unroll
  for (int u = 0; u < 2; ++u) {        // 512 float4 units = 8 rows x 64
    int idx = (u << 8) + tid;
    int row = idx >> 6, c4 = idx & 63;
    int gr = r0 + row, l = gr & 1023;
    float4 xv = ((const float4*)(x + (size_t)gr * 256))[c4];
    float4 pv = ((const float4*)(pe + (size_t)l * 256))[c4];
    int c = c4 << 2;
    xs[row][c] = xv.x; xs[row][c + 1] = xv.y;
    xs[row][c + 2] = xv.z; xs[row][c + 3] = xv.w;
    ushort4 pk;
    pk.x = f2bf(xv.x + pv.x); pk.y = f2bf(xv.y + pv.y);
    pk.z = f2bf(xv.z + pv.z); pk.w = f2bf(xv.w + pv.w);
    *(ushort4*)(XP + (size_t)gr * 256 + c) = pk;
  }
  __syncthreads();
  {
    int rr = tid >> 5, h = (tid >> 2) & 7, t4 = tid & 3;
    float acc = 0.f;
    const int d0 = t4 << 6;
#pragma unroll 16
    for (int d = 0; d < 64; ++d) acc += xs[rr][d0 + d] * Wv[(d0 + d) * 8 + h];
    acc += __shfl_down(acc, 1, 4);
    acc += __shfl_down(acc, 2, 4);
    if (t4 == 0) {
      float v = 1.f / (1.f + __expf(-acc));
      int gr = r0 + rr;
      int b = gr >> 10, l = gr & 1023;
      ws[VR_OFF + (h * 4 + b) * 1024 + (1023 - l)] = v;
    }
  }
}

// ---------------------------------------------------------------------------
// qkgemm: Q|K = bf16(XP @ [Wq|Wk] + bias) via MFMA; 4 chains of 8 (K-split).
// ---------------------------------------------------------------------------
__global__ __launch_bounds__(256) void qkgemm_kernel(float* __restrict__ ws,
    const float* __restrict__ bq, const float* __restrict__ bk)
{
  const int tid = threadIdx.x;
  const int w = tid >> 6, lane = tid & 63;
  const int wid = blockIdx.x * 4 + w;
  const int lt = wid & 127;
  const int cp = wid >> 7;           // 0..15 (0..7 -> Q, 8..15 -> K)

  const __hip_bfloat16* XP = (const __hip_bfloat16*)(ws + XP_OFF);
  const __hip_bfloat16* WT = (const __hip_bfloat16*)(ws + WT_OFF);

  const int ln = (lt << 5) + (lane & 31);
  const int dlo = (lane >> 5) << 3;
  const int ca = (cp << 6) + (lane & 31);
  const __hip_bfloat16* xr = XP + ln * 256 + dlo;
  const __hip_bfloat16* ar = WT + ca * 256 + dlo;
  const __hip_bfloat16* br = ar + (32 * 256);

  f32x16 a0 = {0.f,0.f,0.f,0.f,0.f,0.f,0.f,0.f,0.f,0.f,0.f,0.f,0.f,0.f,0.f,0.f};
  f32x16 a1 = {0.f,0.f,0.f,0.f,0.f,0.f,0.f,0.f,0.f,0.f,0.f,0.f,0.f,0.f,0.f,0.f};
  f32x16 b0 = {0.f,0.f,0.f,0.f,0.f,0.f,0.f,0.f,0.f,0.f,0.f,0.f,0.f,0.f,0.f,0.f};
  f32x16 b1 = {0.f,0.f,0.f,0.f,0.f,0.f,0.f,0.f,0.f,0.f,0.f,0.f,0.f,0.f,0.f,0.f};
#pragma unroll
  for (int k = 0; k < 8; ++k) {
    short8 bfA = *(const short8*)(xr + k * 16);
    short8 bfB = *(const short8*)(xr + (k + 8) * 16);
    short8 afa0 = *(const short8*)(ar + k * 16);
    short8 afa1 = *(const short8*)(ar + (k + 8) * 16);
    short8 afb0 = *(const short8*)(br + k * 16);
    short8 afb1 = *(const short8*)(br + (k + 8) * 16);
    a0 = __builtin_amdgcn_mfma_f32_32x32x16_bf16(afa0, bfA, a0, 0, 0, 0);
    a1 = __builtin_amdgcn_mfma_f32_32x32x16_bf16(afa1, bfB, a1, 0, 0, 0);
    b0 = __builtin_amdgcn_mfma_f32_32x32x16_bf16(afb0, bfA, b0, 0, 0, 0);
    b1 = __builtin_amdgcn_mfma_f32_32x32x16_bf16(afb1, bfB, b1, 0, 0, 0);
  }
  f32x16 acca, accb;
#pragma unroll
  for (int r = 0; r < 16; ++r) { acca[r] = a0[r] + a1[r]; accb[r] = b0[r] + b1[r]; }

  const int b = ln >> 10, l = ln & 1023;
  const int hq = cp & 7;
  const int hi4 = (lane >> 5) << 2;
  const float* bias = (cp < 8) ? bq : bk;
  const int cbase = hq << 6;
  __hip_bfloat16* base = (__hip_bfloat16*)ws + ((cp < 8) ? 0 : (size_t)KB_OFF * 2);
  __hip_bfloat16* dst = base + ((((size_t)(hq * 4 + b) << 10) + l) << 6);

#pragma unroll
  for (int q = 0; q < 4; ++q) {
    int hd0 = (q << 3) + hi4;
    float4 bv = *(const float4*)(bias + cbase + hd0);
    ushort4 pk;
    pk.x = f2bf(acca[4 * q + 0] + bv.x);
    pk.y = f2bf(acca[4 * q + 1] + bv.y);
    pk.z = f2bf(acca[4 * q + 2] + bv.z);
    pk.w = f2bf(acca[4 * q + 3] + bv.w);
    *(ushort4*)(dst + hd0) = pk;

    int hd1 = hd0 + 32;
    float4 bw = *(const float4*)(bias + cbase + hd1);
    ushort4 pk2;
    pk2.x = f2bf(accb[4 * q + 0] + bw.x);
    pk2.y = f2bf(accb[4 * q + 1] + bw.y);
    pk2.z = f2bf(accb[4 * q + 2] + bw.z);
    pk2.w = f2bf(accb[4 * q + 3] + bw.w);
    *(ushort4*)(dst + hd1) = pk2;
  }
}

// ---------------------------------------------------------------------------
// attn: unchanged from r21 (proven): LDS-staged K (XOR swizzle), balanced qt,
// fused 2-phase, shfl gather, direct Tpart2 stores, zero atomics.
// ---------------------------------------------------------------------------
__global__ __launch_bounds__(256) void attn_kernel(float* __restrict__ ws)
{
  __shared__ __hip_bfloat16 Ks[256 * 64];   // 32 KB chunk buffer (swizzled)
  __shared__ float smerge[4][32];
  const int tid = threadIdx.x;
  const int w = tid >> 6, lane = tid & 63;
  const int i = blockIdx.x;
  const int hb = i & 31;
  const int j = i >> 5;
  const int qt = (j & 8) ? ((j < 16) ? 23 - j : 55 - j) : j;

  const __hip_bfloat16* Qb = (const __hip_bfloat16*)ws + ((size_t)hb << 16);
  const __hip_bfloat16* Kb = (const __hip_bfloat16*)(ws + KB_OFF) + ((size_t)hb << 16);
  const float* __restrict__ vr = ws + VR_OFF + (hb << 10);

  const int qrow = (qt << 5) + (lane & 31);
  const int dlo = (lane >> 5) << 3;
  const int coff = (lane >> 5) << 2;

  const __hip_bfloat16* qr = Qb + (qrow << 6) + dlo;
  short8 qf0 = *(const short8*)(qr);
  short8 qf1 = *(const short8*)(qr + 16);
  short8 qf2 = *(const short8*)(qr + 32);
  short8 qf3 = *(const short8*)(qr + 48);

#define STAGE8(c)                                                             \
  {                                                                           \
    const float4* src_ = (const float4*)Kb + ((c) << 11);                     \
    _Pragma("unroll")                                                         \
    for (int u = 0; u < 8; ++u) {                                             \
      int idx_ = (u << 8) + tid;                                              \
      float4 v_ = src_[idx_];                                                 \
      int row_ = idx_ >> 3;                                                   \
      int colb_ = (idx_ & 7) << 4;                                            \
      *(float4*)((char*)Ks + row_ * 128 + (colb_ ^ ((row_ & 7) << 4))) = v_;  \
    }                                                                         \
  }

#define LDK(tl, kf)                                                           \
  {                                                                           \
    int row_ = ((tl) << 5) + (lane & 31);                                     \
    int sw_ = (row_ & 7) << 4;                                                \
    int cb_ = (lane >> 5) << 4;                                               \
    char* bp_ = (char*)Ks + row_ * 128;                                       \
    kf[0] = *(const short8*)(bp_ + ((cb_) ^ sw_));                            \
    kf[1] = *(const short8*)(bp_ + ((cb_ + 32) ^ sw_));                       \
    kf[2] = *(const short8*)(bp_ + ((cb_ + 64) ^ sw_));                       \
    kf[3] = *(const short8*)(bp_ + ((cb_ + 96) ^ sw_));                       \
  }

  float sp0 = 0.f, sp1 = 0.f, sp2 = 0.f, sp3 = 0.f;
  for (int c = 0; c < 4; ++c) {
    if (c) __syncthreads();
    STAGE8(c);
    __syncthreads();
    short8 ka[4], kb[4];
    LDK(w, ka);
    LDK(w + 4, kb);
    f32x16 acca = {0.f,0.f,0.f,0.f,0.f,0.f,0.f,0.f,0.f,0.f,0.f,0.f,0.f,0.f,0.f,0.f};
    f32x16 accb = {0.f,0.f,0.f,0.f,0.f,0.f,0.f,0.f,0.f,0.f,0.f,0.f,0.f,0.f,0.f,0.f};
    acca = __builtin_amdgcn_mfma_f32_32x32x16_bf16(ka[0], qf0, acca, 0, 0, 0);
    accb = __builtin_amdgcn_mfma_f32_32x32x16_bf16(kb[0], qf0, accb, 0, 0, 0);
    acca = __builtin_amdgcn_mfma_f32_32x32x16_bf16(ka[1], qf1, acca, 0, 0, 0);
    accb = __builtin_amdgcn_mfma_f32_32x32x16_bf16(kb[1], qf1, accb, 0, 0, 0);
    acca = __builtin_amdgcn_mfma_f32_32x32x16_bf16(ka[2], qf2, acca, 0, 0, 0);
    accb = __builtin_amdgcn_mfma_f32_32x32x16_bf16(kb[2], qf2, accb, 0, 0, 0);
    acca = __builtin_amdgcn_mfma_f32_32x32x16_bf16(ka[3], qf3, acca, 0, 0, 0);
    accb = __builtin_amdgcn_mfma_f32_32x32x16_bf16(kb[3], qf3, accb, 0, 0, 0);
#pragma unroll
    for (int r = 0; r < 16; r += 2) {
      sp0 += __expf(acca[r] * 0.125f);
      sp1 += __expf(acca[r + 1] * 0.125f);
      sp2 += __expf(accb[r] * 0.125f);
      sp3 += __expf(accb[r + 1] * 0.125f);
    }
  }
  float s_part = (sp0 + sp1) + (sp2 + sp3);
  s_part += __shfl_xor(s_part, 32);
  if (lane < 32) smerge[w][lane] = s_part;
  __syncthreads();
  const int q = lane & 31;
  const float inv = 1.f / (smerge[0][q] + smerge[1][q] + smerge[2][q] + smerge[3][q]);

#define FLUSH(dt_, acc_)                                                      \
  {                                                                           \
    const int kt_ = qt + (dt_);                                               \
    const float* vb_ = vr + (kt_ << 5) + coff;                                \
    float4 v0_ = *(const float4*)(vb_);                                       \
    float4 v1_ = *(const float4*)(vb_ + 8);                                   \
    float4 v2_ = *(const float4*)(vb_ + 16);                                  \
    float4 v3_ = *(const float4*)(vb_ + 24);                                  \
    float p_[16];                                                             \
    _Pragma("unroll")                                                         \
    for (int r = 0; r < 16; ++r) {                                            \
      float vv_ = (r < 4) ? (&v0_.x)[r] : (r < 8) ? (&v1_.x)[r - 4]           \
                : (r < 12) ? (&v2_.x)[r - 8] : (&v3_.x)[r - 12];              \
      p_[r] = __expf(acc_[r] * 0.125f) * vv_ * inv;                           \
    }                                                                         \
    float accg_ = 0.f;                                                        \
    _Pragma("unroll")                                                         \
    for (int hi = 0; hi < 2; ++hi)                                            \
      _Pragma("unroll")                                                       \
      for (int r = 0; r < 16; ++r) {                                          \
        const int km_ = (hi << 2) + (r & 3) + ((r >> 2) << 3);                \
        int src_ = ((hi << 5) + km_ + 31 - lane) & 63;                        \
        float g_ = __shfl(p_[r], src_);                                       \
        if (km_ <= lane && km_ >= lane - 31) accg_ += g_;                     \
      }                                                                       \
    ws[TP2_OFF + ((size_t)hb << 16) + ((((qt) << 5) + (dt_)) << 6) + lane] = accg_; \
  }

  const int c0 = qt >> 3;
  for (int c = 3; c >= c0; --c) {
    if (c != 3) {
      __syncthreads();
      STAGE8(c);
      __syncthreads();
    }
    const int kta = (c << 3) + w;
    const int ktb = kta + 4;
    if (kta >= qt) {
      short8 ka[4], kb[4];
      LDK(w, ka);
      LDK(w + 4, kb);
      f32x16 acca = {0.f,0.f,0.f,0.f,0.f,0.f,0.f,0.f,0.f,0.f,0.f,0.f,0.f,0.f,0.f,0.f};
      f32x16 accb = {0.f,0.f,0.f,0.f,0.f,0.f,0.f,0.f,0.f,0.f,0.f,0.f,0.f,0.f,0.f,0.f};
      acca = __builtin_amdgcn_mfma_f32_32x32x16_bf16(ka[0], qf0, acca, 0, 0, 0);
      accb = __builtin_amdgcn_mfma_f32_32x32x16_bf16(kb[0], qf0, accb, 0, 0, 0);
      acca = __builtin_amdgcn_mfma_f32_32x32x16_bf16(ka[1], qf1, acca, 0, 0, 0);
      accb = __builtin_amdgcn_mfma_f32_32x32x16_bf16(kb[1], qf1, accb, 0, 0, 0);
      acca = __builtin_amdgcn_mfma_f32_32x32x16_bf16(ka[2], qf2, acca, 0, 0, 0);
      accb = __builtin_amdgcn_mfma_f32_32x32x16_bf16(kb[2], qf2, accb, 0, 0, 0);
      acca = __builtin_amdgcn_mfma_f32_32x32x16_bf16(ka[3], qf3, acca, 0, 0, 0);
      accb = __builtin_amdgcn_mfma_f32_32x32x16_bf16(kb[3], qf3, accb, 0, 0, 0);
      FLUSH(kta - qt, acca);
      FLUSH(ktb - qt, accb);
    } else if (ktb >= qt) {
      short8 kb[4];
      LDK(w + 4, kb);
      f32x16 accb = {0.f,0.f,0.f,0.f,0.f,0.f,0.f,0.f,0.f,0.f,0.f,0.f,0.f,0.f,0.f,0.f};
      accb = __builtin_amdgcn_mfma_f32_32x32x16_bf16(kb[0], qf0, accb, 0, 0, 0);
      accb = __builtin_amdgcn_mfma_f32_32x32x16_bf16(kb[1], qf1, accb, 0, 0, 0);
      accb = __builtin_amdgcn_mfma_f32_32x32x16_bf16(kb[2], qf2, accb, 0, 0, 0);
      accb = __builtin_amdgcn_mfma_f32_32x32x16_bf16(kb[3], qf3, accb, 0, 0, 0);
      FLUSH(ktb - qt, accb);
    }
  }
}

// ---------------------------------------------------------------------------
// out (FUSED out1+out2): block per (jc, hb) computes T for its 32 j's + 2
// halo (34 values, 8 thr each via shfl), stages in LDS, windows, stores.
// Grid 1024 = (jc 32) x (hb 32).
// ---------------------------------------------------------------------------
__global__ __launch_bounds__(256) void out_kernel(const float* __restrict__ ws,
                                                  float* __restrict__ out)
{
  __shared__ float sT[34];
  const int tid = threadIdx.x;
  const int i = blockIdx.x;
  const int hb = i & 31;
  const int jc = i >> 5;
  const int j0 = jc << 5;
  const float* TP = ws + TP2_OFF + ((size_t)hb << 16);

#define TSUM(jj_, t8_, res_)                                                  \
  {                                                                           \
    float acc_ = 0.f;                                                         \
    if ((jj_) >= 0 && (jj_) < 1024) {                                         \
      const int s_ = (jj_) + 31;                                              \
      _Pragma("unroll")                                                       \
      for (int cand = 0; cand < 2; ++cand) {                                  \
        int dt = (s_ >> 5) - cand;                                            \
        if (dt < 0 || dt > 31) continue;                                      \
        int idx = s_ - (dt << 5);                                             \
        int qmax = 31 - dt;                                                   \
        for (int qt = (t8_); qt <= qmax; qt += 8)                             \
          acc_ += TP[(((qt << 5) + dt) << 6) + idx];                          \
      }                                                                       \
    }                                                                         \
    acc_ += __shfl_down(acc_, 4, 8);                                          \
    acc_ += __shfl_down(acc_, 2, 8);                                          \
    acc_ += __shfl_down(acc_, 1, 8);                                          \
    res_ = acc_;                                                              \
  }

  {
    // phase A: 32 values T[j0-1 .. j0+30], 8 threads each
    int jloc = tid >> 3, t8 = tid & 7;
    float r;
    TSUM(j0 + jloc - 1, t8, r);
    if (t8 == 0) sT[jloc] = r;
  }
  if (tid < 16) {
    // phase B: halo T[j0+31], T[j0+32]
    int jx = tid >> 3, t8 = tid & 7;
    float r;
    TSUM(j0 + 31 + jx, t8, r);
    if (t8 == 0) sT[32 + jx] = r;
  }
  __syncthreads();
  if (tid < 32) {
    int j = j0 + tid;
    float cnt = (j == 0 || j == 1023) ? 2.f : 3.f;
    float v = (sT[tid] + sT[tid + 1] + sT[tid + 2]) / cnt;
    int h = hb >> 2, b = hb & 3;
    out[(((b << 10) + j) << 3) + h] = v;
  }
}

extern "C" void kernel_launch(void* const* d_in, const int* in_sizes, int n_in,
                              void* d_out, int out_size, void* d_ws, size_t ws_size,
                              hipStream_t stream)
{
  const float* x  = (const float*)d_in[0];
  const float* Wq = (const float*)d_in[1];
  const float* bq = (const float*)d_in[2];
  const float* Wk = (const float*)d_in[3];
  const float* bk = (const float*)d_in[4];
  const float* Wv = (const float*)d_in[5];
  const float* pe = (const float*)d_in[6];
  float* ws = (float*)d_ws;
  float* out = (float*)d_out;

  prep_wx_kernel<<<dim3(544), dim3(256), 0, stream>>>(x, Wq, Wk, Wv, pe, ws);
  qkgemm_kernel<<<dim3(512), dim3(256), 0, stream>>>(ws, bq, bk);
  attn_kernel<<<dim3(1024), dim3(256), 0, stream>>>(ws);
  out_kernel<<<dim3(1024), dim3(256), 0, stream>>>(ws, out);
}